// Round 6
// baseline (190.984 us; speedup 1.0000x reference)
//
#include <hip/hip_runtime.h>
#include <hip/hip_bf16.h>
#include <math.h>

// Problem constants
#define BB 8
#define LL 128
#define DD 512
#define EE 64
#define HH 8
#define CC 64        // D/H
#define SLOPE 0.2f
#define EPS 1e-5f

typedef short bf16x8v __attribute__((ext_vector_type(8)));
typedef float f32x4v __attribute__((ext_vector_type(4)));

static __device__ __forceinline__ unsigned short f2bf(float f) {
    union { float f; unsigned u; } v; v.f = f;
    unsigned r = v.u + 0x7FFFu + ((v.u >> 16) & 1u);   // RNE
    return (unsigned short)(r >> 16);
}
static __device__ __forceinline__ float bf2f(unsigned short u) {
    union { unsigned u; float f; } v; v.u = ((unsigned)u) << 16; return v.f;
}

// ---------------------------------------------------------------------------
// pack_all — grid sections by blockIdx.x:
//   [0,256)      x cast (1024x512) -> xb
//   [256,1024)   W transposes: Wq->Ball[0:512], Wkv->Ball[512:1024], Wf->Wf_t
//   [1024,1088)  WqWe fold via MFMA: Ball[1024+hx][d] = bf16(sum_c Wq[d][h64+c]*We[x][h64+c])
//                (R4's fold was scalar+uncoalesced = 47us; this one is an MFMA
//                 tile with 32B-contiguous per-lane reads, L1-amortized)
// ---------------------------------------------------------------------------
__global__ __launch_bounds__(256) void pack_all(
    const float* __restrict__ x, const float* __restrict__ Wq,
    const float* __restrict__ Wkv, const float* __restrict__ Wf,
    const float* __restrict__ We,
    unsigned short* __restrict__ xb, unsigned short* __restrict__ Ball,
    unsigned short* __restrict__ Wf_t)
{
    const int blk = blockIdx.x, tid = threadIdx.x;
    if (blk < 256) {                       // x cast
        const int j = blk * 512 + tid * 2;
        #pragma unroll
        for (int i = 0; i < 2; ++i) {
            const float4 v = ((const float4*)x)[j + i];
            ushort4 u; u.x = f2bf(v.x); u.y = f2bf(v.y); u.z = f2bf(v.z); u.w = f2bf(v.w);
            ((ushort4*)xb)[j + i] = u;
        }
    } else if (blk < 1024) {               // 512x512 transpose-cast
        __shared__ float tile[32][33];
        const int matId = (blk - 256) >> 8;
        const int t = (blk - 256) & 255;
        const float* src = matId == 0 ? Wq : (matId == 1 ? Wkv : Wf);
        unsigned short* dst = matId == 0 ? Ball : (matId == 1 ? Ball + DD * DD : Wf_t);
        const int xx = tid & 31, yy = tid >> 5;
        const int r0 = (t >> 4) * 32, c0 = (t & 15) * 32;
        #pragma unroll
        for (int j = 0; j < 32; j += 8)
            tile[yy + j][xx] = src[(r0 + yy + j) * DD + c0 + xx];
        __syncthreads();
        #pragma unroll
        for (int j = 0; j < 32; j += 8)
            dst[(c0 + yy + j) * DD + r0 + xx] = f2bf(tile[xx][yy + j]);
    } else {                               // WqWe fold: M=512(hx) N=512(d) K=64(c)
        const int blk2 = blk - 1024;       // 0..63
        const int mt = blk2 >> 3, nt = blk2 & 7;
        const int h = mt;                  // m-tile of 64 rows => fixed head
        const int wave = tid >> 6, lane = tid & 63;
        const int quad = lane >> 4, l16 = lane & 15;
        const int xrow = wave * 16 + l16;  // x within head (0..63)
        const int n0 = nt * 64;
        f32x4v acc[4];
        #pragma unroll
        for (int t = 0; t < 4; ++t) acc[t] = (f32x4v){0.f,0.f,0.f,0.f};
        #pragma unroll
        for (int ks = 0; ks < 2; ++ks) {
            const float* ap = We + xrow * DD + h * CC + ks * 32 + quad * 8;
            const float4 a0 = *(const float4*)ap;
            const float4 a1 = *(const float4*)(ap + 4);
            bf16x8v av;
            av[0]=(short)f2bf(a0.x); av[1]=(short)f2bf(a0.y); av[2]=(short)f2bf(a0.z); av[3]=(short)f2bf(a0.w);
            av[4]=(short)f2bf(a1.x); av[5]=(short)f2bf(a1.y); av[6]=(short)f2bf(a1.z); av[7]=(short)f2bf(a1.w);
            #pragma unroll
            for (int t = 0; t < 4; ++t) {
                const float* bp = Wq + (n0 + t * 16 + l16) * DD + h * CC + ks * 32 + quad * 8;
                const float4 b0 = *(const float4*)bp;
                const float4 b1 = *(const float4*)(bp + 4);
                bf16x8v bv;
                bv[0]=(short)f2bf(b0.x); bv[1]=(short)f2bf(b0.y); bv[2]=(short)f2bf(b0.z); bv[3]=(short)f2bf(b0.w);
                bv[4]=(short)f2bf(b1.x); bv[5]=(short)f2bf(b1.y); bv[6]=(short)f2bf(b1.z); bv[7]=(short)f2bf(b1.w);
                acc[t] = __builtin_amdgcn_mfma_f32_16x16x32_bf16(av, bv, acc[t], 0, 0, 0);
            }
        }
        #pragma unroll
        for (int t = 0; t < 4; ++t)
            #pragma unroll
            for (int r = 0; r < 4; ++r)
                Ball[(1024 + mt * 64 + wave * 16 + quad * 4 + r) * DD + n0 + t * 16 + l16] = f2bf(acc[t][r]);
    }
}

// ---------------------------------------------------------------------------
// proj_gemm: [Q|KV|T](1024x1536) = xb(1024x512) @ Ball^T. Epilogue:
//   gn<512 -> Q_bf (bq,d); gn<1024 -> KV_bf (bq,d) + KVT_bf (b,h,c,k=l);
//   gn<1536 -> T_bf (bq, h*64+x)          [proven structure, R4]
// ---------------------------------------------------------------------------
__global__ __launch_bounds__(256) void proj_gemm(
    const unsigned short* __restrict__ A, const unsigned short* __restrict__ Bm,
    unsigned short* __restrict__ Q_bf, unsigned short* __restrict__ KV_bf,
    unsigned short* __restrict__ KVT_bf, unsigned short* __restrict__ T_bf)
{
    const int wave = threadIdx.x >> 6, lane = threadIdx.x & 63;
    const int quad = lane >> 4, l16 = lane & 15;
    const int m0 = blockIdx.y * 64 + wave * 16;
    const int n0 = blockIdx.x * 64;
    const bf16x8v* Ap = (const bf16x8v*)(A + (m0 + l16) * DD) + quad;
    const bf16x8v* Bp = (const bf16x8v*)(Bm + (n0 + l16) * DD) + quad;
    f32x4v acc0 = {0.f,0.f,0.f,0.f}, acc1 = acc0, acc2 = acc0, acc3 = acc0;
    #pragma unroll 4
    for (int k = 0; k < 16; ++k) {
        const bf16x8v a = Ap[k * 4];
        acc0 = __builtin_amdgcn_mfma_f32_16x16x32_bf16(a, Bp[k * 4       ], acc0, 0, 0, 0);
        acc1 = __builtin_amdgcn_mfma_f32_16x16x32_bf16(a, Bp[k * 4 + 1024], acc1, 0, 0, 0);
        acc2 = __builtin_amdgcn_mfma_f32_16x16x32_bf16(a, Bp[k * 4 + 2048], acc2, 0, 0, 0);
        acc3 = __builtin_amdgcn_mfma_f32_16x16x32_bf16(a, Bp[k * 4 + 3072], acc3, 0, 0, 0);
    }
    const f32x4v accs[4] = {acc0, acc1, acc2, acc3};
    const int gm0 = m0 + quad * 4;
    #pragma unroll
    for (int t = 0; t < 4; ++t) {
        const int gn = n0 + t * 16 + l16;
        ushort4 pk;
        pk.x = f2bf(accs[t][0]); pk.y = f2bf(accs[t][1]);
        pk.z = f2bf(accs[t][2]); pk.w = f2bf(accs[t][3]);
        if (gn < 512) {
            Q_bf[(gm0 + 0) * DD + gn] = pk.x;
            Q_bf[(gm0 + 1) * DD + gn] = pk.y;
            Q_bf[(gm0 + 2) * DD + gn] = pk.z;
            Q_bf[(gm0 + 3) * DD + gn] = pk.w;
        } else if (gn < 1024) {
            const int d = gn - 512, h = d >> 6, c = d & 63;
            KV_bf[(gm0 + 0) * DD + d] = pk.x;
            KV_bf[(gm0 + 1) * DD + d] = pk.y;
            KV_bf[(gm0 + 2) * DD + d] = pk.z;
            KV_bf[(gm0 + 3) * DD + d] = pk.w;
            const int b = gm0 >> 7, l0 = gm0 & 127;
            *(ushort4*)&KVT_bf[(((b * HH + h) * CC + c) << 7) + l0] = pk;
        } else {
            const int d = gn - 1024;
            T_bf[(gm0 + 0) * DD + d] = pk.x;
            T_bf[(gm0 + 1) * DD + d] = pk.y;
            T_bf[(gm0 + 2) * DD + d] = pk.z;
            T_bf[(gm0 + 3) * DD + d] = pk.w;
        }
    }
}

// ---------------------------------------------------------------------------
// attn_mega: one block per (b,q). Fuses: S1 = q.kv (VALU), S2 = E@T^T (MFMA),
// leaky+mask, softmax (norm folded), G = P@E^T (MFMA), and the output
// O = P@KV + G@We (VALU, k-contiguous KVT / coalesced We reads).
// No S1/P/G global round-trips. LDS ~32.5 KB -> 4 blocks/CU.
// ---------------------------------------------------------------------------
#define ES 72      // lds_e row stride (ushort)
#define ETS 136    // p_bf row stride (ushort)
__global__ __launch_bounds__(256) void attn_mega(
    const float* __restrict__ e, const int* __restrict__ adj,
    const unsigned short* __restrict__ Q_bf, const unsigned short* __restrict__ KV_bf,
    const unsigned short* __restrict__ KVT_bf, const unsigned short* __restrict__ T_bf,
    const float* __restrict__ We, unsigned short* __restrict__ attn_bf)
{
    __shared__ unsigned short lds_e[LL * ES];     // 18432 B
    __shared__ float s_lds[HH * 132];             //  4224 B (S1, then combined scores)
    __shared__ float p_f32[HH * 132];             //  4224 B
    __shared__ unsigned short p_bf[HH * ETS];     //  2176 B
    __shared__ float qrow_f[DD];                  //  2048 B
    __shared__ float g_f32[HH * 68];              //  2176 B

    const int bq = blockIdx.x;
    const int b = bq >> 7;
    const int tid = threadIdx.x;
    const int wave = tid >> 6, lane = tid & 63, quad = lane >> 4, l16 = lane & 15;

    // ---- stage e tile (bf16) + q row (fp32) ----
    const float4* e4 = (const float4*)(e + (size_t)bq * (LL * EE));
    #pragma unroll
    for (int rep = 0; rep < 8; ++rep) {
        const int j = rep * 256 + tid;
        const float4 v = e4[j];
        const int k = j >> 4, x0 = (j & 15) * 4;
        ushort4 u; u.x = f2bf(v.x); u.y = f2bf(v.y); u.z = f2bf(v.z); u.w = f2bf(v.w);
        *(ushort4*)&lds_e[k * ES + x0] = u;
    }
    #pragma unroll
    for (int i = 0; i < 2; ++i) {
        const int j = i * 256 + tid;
        qrow_f[j] = bf2f(Q_bf[bq * DD + j]);
    }
    __syncthreads();

    // ---- S1[h,k] = q_h . kv_k  (VALU; kv rows L1-amortized) ----
    #pragma unroll
    for (int i = 0; i < 4; ++i) {
        const int p = i * 256 + tid;
        const int h = p >> 7, k = p & 127;
        const unsigned short* kvp = KV_bf + ((b * LL + k) << 9) + h * CC;
        float acc = 0.f;
        #pragma unroll
        for (int c4 = 0; c4 < 16; ++c4) {
            const ushort4 kv4 = *(const ushort4*)(kvp + c4 * 4);
            const float4 q4 = *(const float4*)&qrow_f[h * CC + c4 * 4];
            acc += bf2f(kv4.x) * q4.x + bf2f(kv4.y) * q4.y
                 + bf2f(kv4.z) * q4.z + bf2f(kv4.w) * q4.w;
        }
        s_lds[h * 132 + k] = acc;
    }
    __syncthreads();

    // ---- S2 = E @ T^T (MFMA), combine with S1 in-place, leaky + mask ----
    const int hh = l16 < 8 ? l16 : 7;
    const unsigned short* Trow = T_bf + bq * DD + hh * CC + quad * 8;
    const bf16x8v tb0 = *(const bf16x8v*)(Trow);
    const bf16x8v tb1 = *(const bf16x8v*)(Trow + 32);
    f32x4v sacc[2];
    #pragma unroll
    for (int mt = 0; mt < 2; ++mt) {
        sacc[mt] = (f32x4v){0.f,0.f,0.f,0.f};
        const int kb = wave * 32 + mt * 16;
        const bf16x8v a0 = *(const bf16x8v*)&lds_e[(kb + l16) * ES + quad * 8];
        const bf16x8v a1 = *(const bf16x8v*)&lds_e[(kb + l16) * ES + 32 + quad * 8];
        sacc[mt] = __builtin_amdgcn_mfma_f32_16x16x32_bf16(a0, tb0, sacc[mt], 0, 0, 0);
        sacc[mt] = __builtin_amdgcn_mfma_f32_16x16x32_bf16(a1, tb1, sacc[mt], 0, 0, 0);
    }
    if (l16 < 8) {
        #pragma unroll
        for (int mt = 0; mt < 2; ++mt) {
            const int kk0 = wave * 32 + mt * 16 + quad * 4;
            const float4 s1v = *(const float4*)&s_lds[l16 * 132 + kk0];
            const int4 av = *(const int4*)&adj[bq * LL + kk0];
            const float sv[4] = {s1v.x, s1v.y, s1v.z, s1v.w};
            const int am[4] = {av.x, av.y, av.z, av.w};
            float4 o; float* op = (float*)&o;
            #pragma unroll
            for (int r = 0; r < 4; ++r) {
                float sc = (sv[r] + sacc[mt][r]) * 0.125f;
                sc = (sc >= 0.f) ? sc : SLOPE * sc;
                op[r] = (am[r] == 0) ? -1e9f : sc;
            }
            *(float4*)&s_lds[l16 * 132 + kk0] = o;
        }
    }
    __syncthreads();

    // ---- softmax per head (32 thr/head), norm folded into P ----
    {
        const int h = tid >> 5, t5 = tid & 31;
        float m = -INFINITY;
        #pragma unroll
        for (int i = 0; i < 4; ++i) m = fmaxf(m, s_lds[h * 132 + t5 + i * 32]);
        #pragma unroll
        for (int off = 16; off > 0; off >>= 1) m = fmaxf(m, __shfl_down(m, off, 32));
        m = __shfl(m, 0, 32);
        const int k0 = t5 * 4;
        float ev[4];
        #pragma unroll
        for (int i = 0; i < 4; ++i) ev[i] = expf(s_lds[h * 132 + k0 + i] - m);
        float l = ev[0] + ev[1] + ev[2] + ev[3];
        #pragma unroll
        for (int off = 16; off > 0; off >>= 1) l += __shfl_down(l, off, 32);
        l = __shfl(l, 0, 32);
        const float inv = 1.f / l;
        const float4 pv = {ev[0] * inv, ev[1] * inv, ev[2] * inv, ev[3] * inv};
        *(float4*)&p_f32[h * 132 + k0] = pv;
        ushort4 pk;
        pk.x = f2bf(pv.x); pk.y = f2bf(pv.y); pk.z = f2bf(pv.z); pk.w = f2bf(pv.w);
        *(ushort4*)&p_bf[h * ETS + k0] = pk;
    }
    __syncthreads();

    // ---- G = P @ E^T (MFMA, B-frags gathered from lds_e) -> g_f32 ----
    {
        const int hr = l16 < 8 ? l16 : 0;
        f32x4v g = {0.f,0.f,0.f,0.f};
        #pragma unroll
        for (int ks = 0; ks < 4; ++ks) {
            const bf16x8v a = *(const bf16x8v*)&p_bf[hr * ETS + ks * 32 + quad * 8];
            bf16x8v bb;
            #pragma unroll
            for (int j = 0; j < 8; ++j)
                bb[j] = (short)lds_e[(ks * 32 + quad * 8 + j) * ES + wave * 16 + l16];
            g = __builtin_amdgcn_mfma_f32_16x16x32_bf16(a, bb, g, 0, 0, 0);
        }
        if (quad < 2) {
            #pragma unroll
            for (int r = 0; r < 4; ++r)
                g_f32[(quad * 4 + r) * 68 + wave * 16 + l16] = g[r];
        }
    }
    __syncthreads();

    // ---- O[h,c] = sum_k P[h,k]*KV[k,h,c] + sum_x G[h,x]*We[x,h*64+c] ----
    #pragma unroll
    for (int i = 0; i < 2; ++i) {
        const int d = i * 256 + tid;
        const int h = d >> 6, c = d & 63;
        const unsigned short* kvtp = KVT_bf + (((b * HH + h) * CC + c) << 7);
        float acc = 0.f;
        #pragma unroll 4
        for (int k8 = 0; k8 < 16; ++k8) {
            const ushort4 a0 = *(const ushort4*)(kvtp + k8 * 8);
            const ushort4 a1 = *(const ushort4*)(kvtp + k8 * 8 + 4);
            const float4 p0 = *(const float4*)&p_f32[h * 132 + k8 * 8];
            const float4 p1 = *(const float4*)&p_f32[h * 132 + k8 * 8 + 4];
            acc += bf2f(a0.x) * p0.x + bf2f(a0.y) * p0.y
                 + bf2f(a0.z) * p0.z + bf2f(a0.w) * p0.w
                 + bf2f(a1.x) * p1.x + bf2f(a1.y) * p1.y
                 + bf2f(a1.z) * p1.z + bf2f(a1.w) * p1.w;
        }
        const float* wep = We + h * CC + c;
        float acc2 = 0.f;
        #pragma unroll 8
        for (int xx = 0; xx < EE; ++xx)
            acc2 += g_f32[h * 68 + xx] * wep[xx * DD];
        attn_bf[bq * DD + d] = f2bf(acc + acc2);
    }
}

// ---------------------------------------------------------------------------
// ffn_ln: block = 16 rows x full N=512. GEMM (K=512) + bias, then LayerNorm
// + ReLU fused in the epilogue (shfl-xor(16) + cross-wave LDS reduce).
// ---------------------------------------------------------------------------
__global__ __launch_bounds__(256) void ffn_ln(
    const unsigned short* __restrict__ A, const unsigned short* __restrict__ Bm,
    const float* __restrict__ bfv, const float* __restrict__ gamma,
    const float* __restrict__ beta, float* __restrict__ out)
{
    __shared__ float red_s[4][16];
    __shared__ float red_ss[4][16];
    __shared__ float st_mu[16];
    __shared__ float st_rs[16];

    const int wave = threadIdx.x >> 6, lane = threadIdx.x & 63;
    const int quad = lane >> 4, l16 = lane & 15;
    const int m0 = blockIdx.x * 16;
    f32x4v acc[8];
    #pragma unroll
    for (int t = 0; t < 8; ++t) acc[t] = (f32x4v){0.f,0.f,0.f,0.f};

    const unsigned short* Ap = A + (m0 + l16) * DD + quad * 8;
    #pragma unroll 2
    for (int k = 0; k < 16; ++k) {
        const bf16x8v a = *(const bf16x8v*)(Ap + k * 32);
        #pragma unroll
        for (int t = 0; t < 8; ++t) {
            const bf16x8v bb = *(const bf16x8v*)(Bm + (wave * 128 + t * 16 + l16) * DD + k * 32 + quad * 8);
            acc[t] = __builtin_amdgcn_mfma_f32_16x16x32_bf16(a, bb, acc[t], 0, 0, 0);
        }
    }
    float ps[4] = {0.f,0.f,0.f,0.f}, pss[4] = {0.f,0.f,0.f,0.f};
    #pragma unroll
    for (int t = 0; t < 8; ++t) {
        const float bias = bfv[wave * 128 + t * 16 + l16];
        #pragma unroll
        for (int r = 0; r < 4; ++r) {
            const float v = acc[t][r] + bias;
            acc[t][r] = v;
            ps[r] += v;
            pss[r] += v * v;
        }
    }
    #pragma unroll
    for (int off = 1; off < 16; off <<= 1) {
        #pragma unroll
        for (int r = 0; r < 4; ++r) {
            ps[r]  += __shfl_xor(ps[r],  off, 16);
            pss[r] += __shfl_xor(pss[r], off, 16);
        }
    }
    if (l16 == 0) {
        #pragma unroll
        for (int r = 0; r < 4; ++r) {
            red_s[wave][quad * 4 + r]  = ps[r];
            red_ss[wave][quad * 4 + r] = pss[r];
        }
    }
    __syncthreads();
    if (threadIdx.x < 16) {
        const int row = threadIdx.x;
        float ts = 0.f, tss = 0.f;
        #pragma unroll
        for (int w = 0; w < 4; ++w) { ts += red_s[w][row]; tss += red_ss[w][row]; }
        const float mu = ts / (float)DD;
        const float var = tss / (float)DD - mu * mu;
        st_mu[row] = mu;
        st_rs[row] = rsqrtf(var + EPS);
    }
    __syncthreads();
    #pragma unroll
    for (int r = 0; r < 4; ++r) {
        const int row = quad * 4 + r;
        const float mu = st_mu[row], rs = st_rs[row];
        #pragma unroll
        for (int t = 0; t < 8; ++t) {
            const int gn = wave * 128 + t * 16 + l16;
            const float o = (acc[t][r] - mu) * rs * gamma[gn] + beta[gn];
            out[(m0 + row) * DD + gn] = fmaxf(o, 0.f);
        }
    }
}

// ---------------------------------------------------------------------------
extern "C" void kernel_launch(void* const* d_in, const int* in_sizes, int n_in,
                              void* d_out, int out_size, void* d_ws, size_t ws_size,
                              hipStream_t stream)
{
    const float* x    = (const float*)d_in[0];
    const int*   adj  = (const int*)  d_in[1];
    const float* e    = (const float*)d_in[2];
    const float* Wq   = (const float*)d_in[3];
    const float* Wkv  = (const float*)d_in[4];
    const float* We   = (const float*)d_in[5];
    const float* Wf   = (const float*)d_in[6];
    const float* bf   = (const float*)d_in[7];
    const float* gam  = (const float*)d_in[8];
    const float* bet  = (const float*)d_in[9];
    float* out = (float*)d_out;

    const int MROW = BB * LL;                    // 1024
    char* w = (char*)d_ws;
    unsigned short* Ball    = (unsigned short*)(w);                 // 1536x512 = 1.5 MB
    unsigned short* xb      = (unsigned short*)(w + (2u << 20));    // 1 MB
    unsigned short* Q_bf    = (unsigned short*)(w + (3u << 20));    // 1 MB
    unsigned short* KV_bf   = (unsigned short*)(w + (4u << 20));    // 1 MB
    unsigned short* KVT_bf  = (unsigned short*)(w + (5u << 20));    // 1 MB
    unsigned short* T_bf    = (unsigned short*)(w + (6u << 20));    // 1 MB
    unsigned short* attn_bf = (unsigned short*)(w + (7u << 20));    // 1 MB
    unsigned short* Wf_t    = (unsigned short*)(w + (8u << 20));    // 0.5 MB

    pack_all<<<1088, 256, 0, stream>>>(x, Wq, Wkv, Wf, We, xb, Ball, Wf_t);
    proj_gemm<<<dim3(24, 16), 256, 0, stream>>>(xb, Ball, Q_bf, KV_bf, KVT_bf, T_bf);
    attn_mega<<<MROW, 256, 0, stream>>>(e, adj, Q_bf, KV_bf, KVT_bf, T_bf, We, attn_bf);
    ffn_ln<<<64, 256, 0, stream>>>(attn_bf, Wf_t, bf, gam, bet, out);
}

// Round 7
// 148.422 us; speedup vs baseline: 1.2868x; 1.2868x over previous
//
#include <hip/hip_runtime.h>
#include <hip/hip_bf16.h>
#include <math.h>

// Problem constants
#define BB 8
#define LL 128
#define DD 512
#define EE 64
#define HH 8
#define CC 64        // D/H
#define SLOPE 0.2f
#define EPS 1e-5f

typedef short bf16x8v __attribute__((ext_vector_type(8)));
typedef float f32x4v __attribute__((ext_vector_type(4)));

static __device__ __forceinline__ unsigned short f2bf(float f) {
    union { float f; unsigned u; } v; v.f = f;
    unsigned r = v.u + 0x7FFFu + ((v.u >> 16) & 1u);   // RNE
    return (unsigned short)(r >> 16);
}

// ---------------------------------------------------------------------------
// pack_all — proven R3 version. Sections by blockIdx.x:
//   [0,256)      x cast (1024x512) -> xb
//   [256,1024)   W transposes: Wq->Wqkv_t[0:512], Wkv->Wqkv_t[512:1024], Wf->Wf_t
//   [1024,1040)  We cast (64x512) -> We_bf
//   [1040,1072)  WeT: We(64x512) -> WeT_bf(512x64)
// ---------------------------------------------------------------------------
__global__ __launch_bounds__(256) void pack_all(
    const float* __restrict__ x, const float* __restrict__ Wq,
    const float* __restrict__ Wkv, const float* __restrict__ Wf,
    const float* __restrict__ We,
    unsigned short* __restrict__ xb, unsigned short* __restrict__ Wqkv_t,
    unsigned short* __restrict__ Wf_t, unsigned short* __restrict__ We_bf,
    unsigned short* __restrict__ WeT_bf)
{
    const int blk = blockIdx.x, tid = threadIdx.x;
    if (blk < 256) {                       // x cast
        const int j = blk * 512 + tid * 2;
        #pragma unroll
        for (int i = 0; i < 2; ++i) {
            const float4 v = ((const float4*)x)[j + i];
            ushort4 u; u.x = f2bf(v.x); u.y = f2bf(v.y); u.z = f2bf(v.z); u.w = f2bf(v.w);
            ((ushort4*)xb)[j + i] = u;
        }
    } else if (blk < 1024) {               // 512x512 transpose-cast
        __shared__ float tile[32][33];
        const int matId = (blk - 256) >> 8;
        const int t = (blk - 256) & 255;
        const float* src = matId == 0 ? Wq : (matId == 1 ? Wkv : Wf);
        unsigned short* dst = matId == 0 ? Wqkv_t : (matId == 1 ? Wqkv_t + DD * DD : Wf_t);
        const int xx = tid & 31, yy = tid >> 5;
        const int r0 = (t >> 4) * 32, c0 = (t & 15) * 32;
        #pragma unroll
        for (int j = 0; j < 32; j += 8)
            tile[yy + j][xx] = src[(r0 + yy + j) * DD + c0 + xx];
        __syncthreads();
        #pragma unroll
        for (int j = 0; j < 32; j += 8)
            dst[(c0 + yy + j) * DD + r0 + xx] = f2bf(tile[xx][yy + j]);
    } else if (blk < 1040) {               // We cast
        const int j = (blk - 1024) * 512 + tid * 2;
        #pragma unroll
        for (int i = 0; i < 2; ++i) {
            const float4 v = ((const float4*)We)[j + i];
            ushort4 u; u.x = f2bf(v.x); u.y = f2bf(v.y); u.z = f2bf(v.z); u.w = f2bf(v.w);
            ((ushort4*)We_bf)[j + i] = u;
        }
    } else {                               // WeT: We(64x512) -> (512x64)
        __shared__ float tile[32][33];
        const int t = blk - 1040;
        const int xx = tid & 31, yy = tid >> 5;
        const int r0 = (t >> 4) * 32, c0 = (t & 15) * 32;
        #pragma unroll
        for (int j = 0; j < 32; j += 8)
            tile[yy + j][xx] = We[(r0 + yy + j) * DD + c0 + xx];
        __syncthreads();
        #pragma unroll
        for (int j = 0; j < 32; j += 8)
            WeT_bf[(c0 + yy + j) * EE + r0 + xx] = f2bf(tile[xx][yy + j]);
    }
}

// ---------------------------------------------------------------------------
// proj_gemm: [Q|KV](1024x1024) = xb(1024x512) @ [Wq|Wkv]. Epilogue writes
// Q_bf, KV_bf (bq,d) bf16 and KVT_bf (b,h,c,k=l) bf16.   [proven R3]
// ---------------------------------------------------------------------------
__global__ __launch_bounds__(256) void proj_gemm(
    const unsigned short* __restrict__ A, const unsigned short* __restrict__ Bm,
    unsigned short* __restrict__ Q_bf, unsigned short* __restrict__ KV_bf,
    unsigned short* __restrict__ KVT_bf)
{
    const int wave = threadIdx.x >> 6, lane = threadIdx.x & 63;
    const int quad = lane >> 4, l16 = lane & 15;
    const int m0 = blockIdx.y * 64 + wave * 16;
    const int n0 = blockIdx.x * 64;
    const bf16x8v* Ap = (const bf16x8v*)(A + (m0 + l16) * DD) + quad;
    const bf16x8v* Bp = (const bf16x8v*)(Bm + (n0 + l16) * DD) + quad;
    f32x4v acc0 = {0.f,0.f,0.f,0.f}, acc1 = acc0, acc2 = acc0, acc3 = acc0;
    #pragma unroll 4
    for (int k = 0; k < 16; ++k) {
        const bf16x8v a = Ap[k * 4];
        acc0 = __builtin_amdgcn_mfma_f32_16x16x32_bf16(a, Bp[k * 4       ], acc0, 0, 0, 0);
        acc1 = __builtin_amdgcn_mfma_f32_16x16x32_bf16(a, Bp[k * 4 + 1024], acc1, 0, 0, 0);
        acc2 = __builtin_amdgcn_mfma_f32_16x16x32_bf16(a, Bp[k * 4 + 2048], acc2, 0, 0, 0);
        acc3 = __builtin_amdgcn_mfma_f32_16x16x32_bf16(a, Bp[k * 4 + 3072], acc3, 0, 0, 0);
    }
    const f32x4v accs[4] = {acc0, acc1, acc2, acc3};
    const int gm0 = m0 + quad * 4;
    #pragma unroll
    for (int t = 0; t < 4; ++t) {
        const int gn = n0 + t * 16 + l16;
        const int mat = gn >> 9, d = gn & 511, h = d >> 6, c = d & 63;
        unsigned short* dst = mat ? KV_bf : Q_bf;
        ushort4 pk;
        pk.x = f2bf(accs[t][0]); pk.y = f2bf(accs[t][1]);
        pk.z = f2bf(accs[t][2]); pk.w = f2bf(accs[t][3]);
        dst[(gm0 + 0) * DD + d] = pk.x;
        dst[(gm0 + 1) * DD + d] = pk.y;
        dst[(gm0 + 2) * DD + d] = pk.z;
        dst[(gm0 + 3) * DD + d] = pk.w;
        if (mat) {
            const int b = gm0 >> 7, l0 = gm0 & 127;
            *(ushort4*)&KVT_bf[(((b * HH + h) * CC + c) << 7) + l0] = pk;
        }
    }
}

// ---------------------------------------------------------------------------
// qk_t_gemm: blockIdx.x<256: S1[b,h,q,k] = Q_h @ KV_h^T (fp32).
//            blockIdx.x>=256: T_bf[bq, h*64+x] = Q_h @ We_h^T (bf16). [proven R3]
// ---------------------------------------------------------------------------
__global__ __launch_bounds__(256) void qk_t_gemm(
    const unsigned short* __restrict__ Q_bf, const unsigned short* __restrict__ KV_bf,
    const unsigned short* __restrict__ We_bf,
    float* __restrict__ S1, unsigned short* __restrict__ T_bf)
{
    const int wave = threadIdx.x >> 6, lane = threadIdx.x & 63;
    const int quad = lane >> 4, l16 = lane & 15;
    const int bid = blockIdx.x;
    f32x4v acc[4];
    #pragma unroll
    for (int t = 0; t < 4; ++t) acc[t] = (f32x4v){0.f,0.f,0.f,0.f};

    if (bid < 256) {
        const int batch = bid >> 2, sub = bid & 3;
        const int b = batch >> 3, h = batch & 7;
        const int q0 = (sub >> 1) * 64 + wave * 16;
        const int k0 = (sub & 1) * 64;
        const unsigned short* Ap = Q_bf + (b * LL + q0 + l16) * DD + h * CC + quad * 8;
        #pragma unroll
        for (int ks = 0; ks < 2; ++ks) {
            const bf16x8v a = *(const bf16x8v*)(Ap + ks * 32);
            #pragma unroll
            for (int t = 0; t < 4; ++t) {
                const bf16x8v bb = *(const bf16x8v*)(KV_bf + (b * LL + k0 + t * 16 + l16) * DD + h * CC + quad * 8 + ks * 32);
                acc[t] = __builtin_amdgcn_mfma_f32_16x16x32_bf16(a, bb, acc[t], 0, 0, 0);
            }
        }
        #pragma unroll
        for (int t = 0; t < 4; ++t)
            #pragma unroll
            for (int r = 0; r < 4; ++r)
                S1[((batch * LL + q0 + quad * 4 + r) << 7) + k0 + t * 16 + l16] = acc[t][r];
    } else {
        const int bid2 = bid - 256;
        const int h = bid2 >> 4;
        const int m0 = (bid2 & 15) * 64 + wave * 16;
        const unsigned short* Ap = Q_bf + (m0 + l16) * DD + h * CC + quad * 8;
        #pragma unroll
        for (int ks = 0; ks < 2; ++ks) {
            const bf16x8v a = *(const bf16x8v*)(Ap + ks * 32);
            #pragma unroll
            for (int t = 0; t < 4; ++t) {
                const bf16x8v bb = *(const bf16x8v*)(We_bf + (t * 16 + l16) * DD + h * CC + quad * 8 + ks * 32);
                acc[t] = __builtin_amdgcn_mfma_f32_16x16x32_bf16(a, bb, acc[t], 0, 0, 0);
            }
        }
        #pragma unroll
        for (int t = 0; t < 4; ++t)
            #pragma unroll
            for (int r = 0; r < 4; ++r)
                T_bf[(m0 + quad * 4 + r) * DD + h * CC + t * 16 + l16] = f2bf(acc[t][r]);
    }
}

// ---------------------------------------------------------------------------
// attn_fused: one block per (b,q). Single e-layout, ES=66 ushorts:
//   gather bank = (33*row + col) % 32; rows 8 apart differ by 8 banks,
//   quads span {0,8,16,24}, cols span 8 -> all 32 banks, conflict-free.
// LDS ~23 KB -> ~6 blocks/CU.
// ---------------------------------------------------------------------------
#define ES 66      // lds_e row stride (ushort) — conflict-free gather
#define ETS 136    // p_bf row stride (ushort)
__global__ __launch_bounds__(256) void attn_fused(
    const float* __restrict__ e, const int* __restrict__ adj,
    const float* __restrict__ S1, const unsigned short* __restrict__ T_bf,
    unsigned short* __restrict__ P1, unsigned short* __restrict__ G_bf)
{
    __shared__ unsigned short lds_e[LL * ES];     // 16896 B
    __shared__ float s_lds[HH * 132];             //  4224 B
    __shared__ unsigned short p_bf[HH * ETS];     //  2176 B

    const int bq = blockIdx.x;
    const int b = bq >> 7, q = bq & 127;
    const int tid = threadIdx.x;
    const int wave = tid >> 6, lane = tid & 63, quad = lane >> 4, l16 = lane & 15;

    // ---- stage e tile (coalesced float4 reads, bf16 LDS) ----
    const float4* e4 = (const float4*)(e + (size_t)bq * (LL * EE));
    #pragma unroll
    for (int rep = 0; rep < 8; ++rep) {
        const int j = rep * 256 + tid;
        const float4 v = e4[j];
        const int k = j >> 4, x0 = (j & 15) * 4;
        ushort4 u; u.x = f2bf(v.x); u.y = f2bf(v.y); u.z = f2bf(v.z); u.w = f2bf(v.w);
        *(ushort4*)&lds_e[k * ES + x0] = u;
    }
    __syncthreads();

    // ---- scores: wave handles k-band [wave*32, +32) ----
    const int hh = l16 < 8 ? l16 : 7;
    const unsigned short* Trow = T_bf + bq * DD + hh * CC + quad * 8;
    const bf16x8v tb0 = *(const bf16x8v*)(Trow);
    const bf16x8v tb1 = *(const bf16x8v*)(Trow + 32);
    f32x4v sacc[2];
    #pragma unroll
    for (int mt = 0; mt < 2; ++mt) {
        sacc[mt] = (f32x4v){0.f,0.f,0.f,0.f};
        const int kb = wave * 32 + mt * 16;
        const bf16x8v a0 = *(const bf16x8v*)&lds_e[(kb + l16) * ES + quad * 8];
        const bf16x8v a1 = *(const bf16x8v*)&lds_e[(kb + l16) * ES + 32 + quad * 8];
        sacc[mt] = __builtin_amdgcn_mfma_f32_16x16x32_bf16(a0, tb0, sacc[mt], 0, 0, 0);
        sacc[mt] = __builtin_amdgcn_mfma_f32_16x16x32_bf16(a1, tb1, sacc[mt], 0, 0, 0);
    }
    if (l16 < 8) {
        #pragma unroll
        for (int mt = 0; mt < 2; ++mt) {
            const int kk0 = wave * 32 + mt * 16 + quad * 4;
            const float4 s1v = *(const float4*)&S1[(((b * HH + l16) * LL + q) << 7) + kk0];
            const int4 av = *(const int4*)&adj[bq * LL + kk0];
            const float sv[4] = {s1v.x, s1v.y, s1v.z, s1v.w};
            const int am[4] = {av.x, av.y, av.z, av.w};
            float4 o; float* op = (float*)&o;
            #pragma unroll
            for (int r = 0; r < 4; ++r) {
                float sc = (sv[r] + sacc[mt][r]) * 0.125f;
                sc = (sc >= 0.f) ? sc : SLOPE * sc;
                op[r] = (am[r] == 0) ? -1e9f : sc;
            }
            *(float4*)&s_lds[l16 * 132 + kk0] = o;
        }
    }
    __syncthreads();

    // ---- softmax per head (32 threads/head), norm folded into P ----
    {
        const int h = tid >> 5, t5 = tid & 31;
        float m = -INFINITY;
        #pragma unroll
        for (int i = 0; i < 4; ++i) m = fmaxf(m, s_lds[h * 132 + t5 + i * 32]);
        #pragma unroll
        for (int off = 16; off > 0; off >>= 1) m = fmaxf(m, __shfl_down(m, off, 32));
        m = __shfl(m, 0, 32);
        const int k0 = t5 * 4;
        float ev[4];
        #pragma unroll
        for (int i = 0; i < 4; ++i) ev[i] = expf(s_lds[h * 132 + k0 + i] - m);
        float l = ev[0] + ev[1] + ev[2] + ev[3];
        #pragma unroll
        for (int off = 16; off > 0; off >>= 1) l += __shfl_down(l, off, 32);
        l = __shfl(l, 0, 32);
        const float inv = 1.f / l;
        ushort4 pk;
        pk.x = f2bf(ev[0] * inv); pk.y = f2bf(ev[1] * inv);
        pk.z = f2bf(ev[2] * inv); pk.w = f2bf(ev[3] * inv);
        *(ushort4*)&p_bf[h * ETS + k0] = pk;
        *(ushort4*)&P1[(((b * HH + h) * LL + q) << 7) + k0] = pk;
    }
    __syncthreads();

    // ---- G = P @ E^T : wave covers x-band [wave*16, +16), gather B-frags ----
    {
        const int hr = l16 < 8 ? l16 : 0;
        f32x4v g = {0.f,0.f,0.f,0.f};
        #pragma unroll
        for (int ks = 0; ks < 4; ++ks) {
            const bf16x8v a = *(const bf16x8v*)&p_bf[hr * ETS + ks * 32 + quad * 8];
            bf16x8v bb;
            #pragma unroll
            for (int j = 0; j < 8; ++j)
                bb[j] = (short)lds_e[(ks * 32 + quad * 8 + j) * ES + wave * 16 + l16];
            g = __builtin_amdgcn_mfma_f32_16x16x32_bf16(a, bb, g, 0, 0, 0);
        }
        if (quad < 2) {
            #pragma unroll
            for (int r = 0; r < 4; ++r)
                G_bf[bq * DD + (quad * 4 + r) * CC + wave * 16 + l16] = f2bf(g[r]);
        }
    }
}

// ---------------------------------------------------------------------------
// out_gemm: attn_bf[b,q, h*64+c] = bf16( P1_h @ KV_h  +  G_h @ We_h )
// 128 threads (2 waves), M=32 rows/block -> 256 blocks.
// ---------------------------------------------------------------------------
__global__ __launch_bounds__(128) void out_gemm(
    const unsigned short* __restrict__ P1, const unsigned short* __restrict__ KVT_bf,
    const unsigned short* __restrict__ G_bf, const unsigned short* __restrict__ WeT_bf,
    unsigned short* __restrict__ attn_bf)
{
    const int wave = threadIdx.x >> 6, lane = threadIdx.x & 63;
    const int quad = lane >> 4, l16 = lane & 15;
    const int batch = blockIdx.x >> 2;           // b*8+h
    const int q0 = (blockIdx.x & 3) * 32 + wave * 16;
    const int b = batch >> 3, h = batch & 7;
    f32x4v acc[4];
    #pragma unroll
    for (int t = 0; t < 4; ++t) acc[t] = (f32x4v){0.f,0.f,0.f,0.f};

    // phase 1: P @ KV  (K = 128 keys)
    const unsigned short* Ap = P1 + ((batch * LL + q0 + l16) << 7) + quad * 8;
    #pragma unroll
    for (int ks = 0; ks < 4; ++ks) {
        const bf16x8v a = *(const bf16x8v*)(Ap + ks * 32);
        #pragma unroll
        for (int t = 0; t < 4; ++t) {
            const bf16x8v bb = *(const bf16x8v*)(KVT_bf + ((batch * CC + t * 16 + l16) << 7) + ks * 32 + quad * 8);
            acc[t] = __builtin_amdgcn_mfma_f32_16x16x32_bf16(a, bb, acc[t], 0, 0, 0);
        }
    }
    // phase 2: G @ We  (K = 64 x)
    const unsigned short* Ap2 = G_bf + (b * LL + q0 + l16) * DD + h * CC + quad * 8;
    #pragma unroll
    for (int ks = 0; ks < 2; ++ks) {
        const bf16x8v a = *(const bf16x8v*)(Ap2 + ks * 32);
        #pragma unroll
        for (int t = 0; t < 4; ++t) {
            const bf16x8v bb = *(const bf16x8v*)(WeT_bf + (h * CC + t * 16 + l16) * EE + ks * 32 + quad * 8);
            acc[t] = __builtin_amdgcn_mfma_f32_16x16x32_bf16(a, bb, acc[t], 0, 0, 0);
        }
    }
    #pragma unroll
    for (int t = 0; t < 4; ++t)
        #pragma unroll
        for (int r = 0; r < 4; ++r)
            attn_bf[(b * LL + q0 + quad * 4 + r) * DD + h * CC + t * 16 + l16] = f2bf(acc[t][r]);
}

// ---------------------------------------------------------------------------
// ffn_ln: 128 blocks, M=8 useful rows/block (A-fragment spans 16 rows; the
// 8 phantom rows read valid-but-unused bf16 data and their outputs are
// discarded). GEMM (K=512) + bias + LayerNorm + ReLU fused.
// ---------------------------------------------------------------------------
__global__ __launch_bounds__(256) void ffn_ln(
    const unsigned short* __restrict__ A, const unsigned short* __restrict__ Bm,
    const float* __restrict__ bfv, const float* __restrict__ gamma,
    const float* __restrict__ beta, float* __restrict__ out)
{
    __shared__ float red_s[4][16];
    __shared__ float red_ss[4][16];
    __shared__ float st_mu[16];
    __shared__ float st_rs[16];

    const int wave = threadIdx.x >> 6, lane = threadIdx.x & 63;
    const int quad = lane >> 4, l16 = lane & 15;
    const int m0 = blockIdx.x * 8;               // 8 useful rows per block
    f32x4v acc[8];
    #pragma unroll
    for (int t = 0; t < 8; ++t) acc[t] = (f32x4v){0.f,0.f,0.f,0.f};

    const unsigned short* Ap = A + (m0 + l16) * DD + quad * 8;
    #pragma unroll 2
    for (int k = 0; k < 16; ++k) {
        const bf16x8v a = *(const bf16x8v*)(Ap + k * 32);
        #pragma unroll
        for (int t = 0; t < 8; ++t) {
            const bf16x8v bb = *(const bf16x8v*)(Bm + (wave * 128 + t * 16 + l16) * DD + k * 32 + quad * 8);
            acc[t] = __builtin_amdgcn_mfma_f32_16x16x32_bf16(a, bb, acc[t], 0, 0, 0);
        }
    }
    float ps[4] = {0.f,0.f,0.f,0.f}, pss[4] = {0.f,0.f,0.f,0.f};
    #pragma unroll
    for (int t = 0; t < 8; ++t) {
        const float bias = bfv[wave * 128 + t * 16 + l16];
        #pragma unroll
        for (int r = 0; r < 4; ++r) {
            const float v = acc[t][r] + bias;
            acc[t][r] = v;
            ps[r] += v;
            pss[r] += v * v;
        }
    }
    #pragma unroll
    for (int off = 1; off < 16; off <<= 1) {
        #pragma unroll
        for (int r = 0; r < 4; ++r) {
            ps[r]  += __shfl_xor(ps[r],  off, 16);
            pss[r] += __shfl_xor(pss[r], off, 16);
        }
    }
    if (l16 == 0) {
        #pragma unroll
        for (int r = 0; r < 4; ++r) {
            red_s[wave][quad * 4 + r]  = ps[r];
            red_ss[wave][quad * 4 + r] = pss[r];
        }
    }
    __syncthreads();
    if (threadIdx.x < 16) {
        const int row = threadIdx.x;
        float ts = 0.f, tss = 0.f;
        #pragma unroll
        for (int w = 0; w < 4; ++w) { ts += red_s[w][row]; tss += red_ss[w][row]; }
        const float mu = ts / (float)DD;
        const float var = tss / (float)DD - mu * mu;
        st_mu[row] = mu;
        st_rs[row] = rsqrtf(var + EPS);
    }
    __syncthreads();
    if (quad < 2) {                              // rows 0..7 are the useful ones
        #pragma unroll
        for (int r = 0; r < 4; ++r) {
            const int row = quad * 4 + r;
            const float mu = st_mu[row], rs = st_rs[row];
            #pragma unroll
            for (int t = 0; t < 8; ++t) {
                const int gn = wave * 128 + t * 16 + l16;
                const float o = (acc[t][r] - mu) * rs * gamma[gn] + beta[gn];
                out[(m0 + row) * DD + gn] = fmaxf(o, 0.f);
            }
        }
    }
}

// ---------------------------------------------------------------------------
extern "C" void kernel_launch(void* const* d_in, const int* in_sizes, int n_in,
                              void* d_out, int out_size, void* d_ws, size_t ws_size,
                              hipStream_t stream)
{
    const float* x    = (const float*)d_in[0];
    const int*   adj  = (const int*)  d_in[1];
    const float* e    = (const float*)d_in[2];
    const float* Wq   = (const float*)d_in[3];
    const float* Wkv  = (const float*)d_in[4];
    const float* We   = (const float*)d_in[5];
    const float* Wf   = (const float*)d_in[6];
    const float* bf   = (const float*)d_in[7];
    const float* gam  = (const float*)d_in[8];
    const float* bet  = (const float*)d_in[9];
    float* out = (float*)d_out;

    const int MROW = BB * LL;                    // 1024
    char* w = (char*)d_ws;
    unsigned short* Wqkv_t  = (unsigned short*)(w);                 // 1 MB
    unsigned short* xb      = (unsigned short*)(w + (1u  << 20));   // 1 MB
    unsigned short* Q_bf    = (unsigned short*)(w + (2u  << 20));   // 1 MB
    unsigned short* KV_bf   = (unsigned short*)(w + (3u  << 20));   // 1 MB
    unsigned short* KVT_bf  = (unsigned short*)(w + (4u  << 20));   // 1 MB
    unsigned short* T_bf    = (unsigned short*)(w + (5u  << 20));   // 1 MB
    float*          S1      = (float*)         (w + (6u  << 20));   // 4 MB
    unsigned short* P1      = (unsigned short*)(w + (10u << 20));   // 2 MB
    unsigned short* G_bf    = (unsigned short*)(w + (12u << 20));   // 1 MB
    unsigned short* attn_bf = (unsigned short*)(w + (13u << 20));   // 1 MB
    unsigned short* Wf_t    = (unsigned short*)(w + (14u << 20));   // 0.5 MB
    unsigned short* We_bf   = (unsigned short*)(w + (14u << 20) + (512u << 10)); // 64 KB
    unsigned short* WeT_bf  = (unsigned short*)(w + (14u << 20) + (576u << 10)); // 64 KB

    pack_all<<<1072, 256, 0, stream>>>(x, Wq, Wkv, Wf, We, xb, Wqkv_t, Wf_t, We_bf, WeT_bf);
    proj_gemm<<<dim3(16, 16), 256, 0, stream>>>(xb, Wqkv_t, Q_bf, KV_bf, KVT_bf);
    qk_t_gemm<<<384, 256, 0, stream>>>(Q_bf, KV_bf, We_bf, S1, T_bf);
    attn_fused<<<MROW, 256, 0, stream>>>(e, adj, S1, T_bf, P1, G_bf);
    out_gemm<<<256, 128, 0, stream>>>(P1, KVT_bf, G_bf, WeT_bf, attn_bf);
    ffn_ln<<<128, 256, 0, stream>>>(attn_bf, Wf_t, bf, gam, bet, out);
}